// Round 12
// baseline (246.503 us; speedup 1.0000x reference)
//
#include <hip/hip_runtime.h>
#include <stdint.h>

// ---------- types ----------
typedef __bf16 bf16x8 __attribute__((ext_vector_type(8)));
typedef float f32x4 __attribute__((ext_vector_type(4)));
typedef unsigned short u16x8 __attribute__((ext_vector_type(8)));
typedef unsigned int as1_uint __attribute__((address_space(1)));
typedef unsigned int as3_uint __attribute__((address_space(3)));

#define N_B 32768
#define S_IN 256
#define H_DIM 512
#define A_DIM 64
#define K1_DIM 2304   // 9 * 256, k = j*256 + i  (j-major, validated r1/r11)
#define K2P 6144      // 512 * 12, k = h*12 + j (h-major, planes 9..11 zero-padded)
#define LDA2P 104     // gemm2 A-tile u16 stride (96 + 8): 52 dw === 20 mod 32, 2-way reads

#define MFMA __builtin_amdgcn_mfma_f32_16x16x32_bf16

static __device__ __forceinline__ unsigned short f2bf(float f) {
  union { float f; unsigned u; } v; v.f = f;
  unsigned r = v.u + 0x7fffu + ((v.u >> 16) & 1u);
  return (unsigned short)(r >> 16);
}

static __device__ __forceinline__ void gload_lds16(const void* g, void* l) {
  __builtin_amdgcn_global_load_lds((const as1_uint*)g, (as3_uint*)l, 16, 0, 0);
}

// 16B-slot swizzle within each 64-u16 K-window, keyed on tile row low bits.
// Involution: stored[c] = logical[swz(c,row)]; readers XOR the slot the same way.
static __device__ __forceinline__ int swz64(int c, int row) {
  return (c & ~63) | ((((c >> 3) & 7) ^ (row & 7)) << 3) | (c & 7);
}

// Uniform-knot cardinal cubic B-spline (validated r1/r2/r11, absmax 0.0625).
static __device__ __forceinline__ void bspline_w(float x, float& c,
    float& w0, float& w1, float& w2, float& w3) {
  float u = fmaf(2.5f, x, 5.5f);
  c = floorf(u);
  float f = u - c;
  float f2 = f * f;
  float f3 = f2 * f;
  const float k6 = 1.f / 6.f;
  w3 = f3 * k6;
  w2 = (3.f * (f + f2 - f3) + 1.f) * k6;
  w1 = (3.f * f3 - 6.f * f2 + 4.f) * k6;
  float omf = 1.f - f;
  w0 = omf * omf * omf * k6;
}

static __device__ __forceinline__ float silu_f(float x) {
  return x / (1.f + __expf(-x));
}

// kan_feat (validated round 2): 9 features of one scalar. s16 = bf16(silu(x));
// spline planes 0..7 packed 2-per-u32 in q0..q3 via 64-bit shift placement.
static __device__ __forceinline__ void kan_feat(float x, unsigned& s16,
    unsigned& q0, unsigned& q1, unsigned& q2, unsigned& q3) {
  s16 = f2bf(silu_f(x));
  float u = fmaf(2.5f, x, 5.5f);
  float cf = floorf(u);
  float f = u - cf;
  float f2 = f * f;
  float f3 = f2 * f;
  const float k6 = 1.f / 6.f;
  float w3v = f3 * k6;
  float w2v = (3.f * (f + f2 - f3) + 1.f) * k6;
  float w1v = (3.f * f3 - 6.f * f2 + 4.f) * k6;
  float omf = 1.f - f;
  float w0v = omf * omf * omf * k6;
  int i0 = (int)cf - 3;
  uint64_t W64 = (uint64_t)((unsigned)f2bf(w0v) | ((unsigned)f2bf(w1v) << 16))
               | ((uint64_t)((unsigned)f2bf(w2v) | ((unsigned)f2bf(w3v) << 16)) << 32);
  uint64_t lo = 0, hi = 0;
  if (i0 >= 0) {
    int s = i0 * 16;
    lo = (i0 < 4) ? (W64 << (s & 63)) : 0;
    uint64_t hr = (i0 >= 1 && i0 < 4) ? (W64 >> ((64 - s) & 63)) : 0;
    uint64_t hl = (i0 >= 4 && i0 < 8) ? (W64 << ((s - 64) & 63)) : 0;
    hi = hr | hl;
  } else {
    lo = (i0 >= -3) ? (W64 >> ((-i0 * 16) & 63)) : 0;
  }
  q0 = (unsigned)lo; q1 = (unsigned)(lo >> 32);
  q2 = (unsigned)hi; q3 = (unsigned)(hi >> 32);
}

// ---------- sentinel (workspace too small diagnostic) ----------
__global__ void k_sentinel(float* out, int n) {
  int i = blockIdx.x * blockDim.x + threadIdx.x;
  for (; i < n; i += gridDim.x * blockDim.x) out[i] = 12345.f;
}

// ---------- W1 prep: f32 -> bf16, j-major K, pre-swizzled 16B slots (r11) ----------
__global__ void k_prep_w1(const float* __restrict__ base_w,
                          const float* __restrict__ spline_w,
                          unsigned short* __restrict__ W1) {
  int idx = blockIdx.x * blockDim.x + threadIdx.x;   // 512*2304
  int n = idx / K1_DIM;
  int c = idx - n * K1_DIM;          // stored col
  int k = swz64(c, n);               // logical col
  int j = k >> 8;
  int i = k & 255;
  float v = (j == 0) ? base_w[n * S_IN + i]
                     : spline_w[(size_t)(n * S_IN + i) * 8 + (j - 1)];
  W1[idx] = f2bf(v);
}

// ---------- W2 prep: h-major padded (k = h*12 + j), plain row-major ----------
__global__ void k_prep_w2(const float* __restrict__ mean_base,
                          const float* __restrict__ mean_spl,
                          const float* __restrict__ lstd_base,
                          const float* __restrict__ lstd_spl,
                          unsigned short* __restrict__ W2p) {
  int idx = blockIdx.x * blockDim.x + threadIdx.x;   // 128*6144 = 786432
  int n = idx / K2P;
  int k = idx - n * K2P;
  int h = k / 12;
  int j = k - h * 12;
  const float* bw = (n < 64) ? mean_base : lstd_base;
  const float* sw = (n < 64) ? mean_spl : lstd_spl;
  int nn = n & 63;
  float v = 0.f;
  if (j == 0) v = bw[nn * H_DIM + h];
  else if (j <= 8) v = sw[(size_t)(nn * H_DIM + h) * 8 + (j - 1)];
  W2p[idx] = f2bf(v);
}

// ---------- layer-1 features: state[B][256] -> F1[B][2304] bf16 (r11) ----------
__global__ void k_features1(const float* __restrict__ state,
                            unsigned short* __restrict__ F1) {
  int tid = blockIdx.x * blockDim.x + threadIdx.x;   // < 2097152
  int base = tid * 4;
  int b = base >> 8;
  int i = base & 255;
  const float4 xv = *(const float4*)(state + base);
  float xs[4] = {xv.x, xv.y, xv.z, xv.w};
  unsigned short outj[9][4];
  #pragma unroll
  for (int e = 0; e < 4; ++e) {
    float x = xs[e];
    float c, w0, w1, w2, w3;
    bspline_w(x, c, w0, w1, w2, w3);
    outj[0][e] = f2bf(silu_f(x));
    #pragma unroll
    for (int g = 0; g < 8; ++g) {
      float d = c - (float)g;
      float v = 0.f;
      v = (d == 0.f) ? w3 : v;
      v = (d == 1.f) ? w2 : v;
      v = (d == 2.f) ? w1 : v;
      v = (d == 3.f) ? w0 : v;
      outj[g + 1][e] = f2bf(v);
    }
  }
  size_t rowbase = (size_t)b * K1_DIM;
  #pragma unroll
  for (int j = 0; j < 9; ++j) {
    int c = swz64(j * S_IN + i, b);
    *(ushort4*)(F1 + rowbase + c) =
        make_ushort4(outj[j][0], outj[j][1], outj[j][2], outj[j][3]);
  }
}

// ---------- GEMM1: X[32768][512] = F1 @ W1^T  (r11, unchanged) ----------
__global__ __launch_bounds__(256, 2) void k_gemm1(
    const unsigned short* __restrict__ F1,
    const unsigned short* __restrict__ W1,
    float* __restrict__ X) {
  extern __shared__ unsigned short smem[];
  unsigned short* As0 = smem;            // [128][64] swizzled image
  unsigned short* As1 = smem + 8192;
  unsigned short* Bs0 = smem + 16384;
  unsigned short* Bs1 = smem + 24576;

  const int t = threadIdx.x;
  const int bid = (int)(blockIdx.x & 7) * 128 + ((int)blockIdx.x >> 3);
  const int bm = bid >> 2;               // 0..255
  const int bn = bid & 3;                // 0..3

  const unsigned short* Ab = F1 + (size_t)bm * 128 * K1_DIM;
  const unsigned short* Bb = W1 + (size_t)bn * 128 * K1_DIM;

  const int srow = t >> 3;               // 0..31
  const int scol = (t & 7) * 8;          // 16B chunks

  auto stage = [&](int buf, int kt) {
    unsigned short* Ad = buf ? As1 : As0;
    unsigned short* Bd = buf ? Bs1 : Bs0;
    const size_t k0 = (size_t)kt * 64;
    #pragma unroll
    for (int q = 0; q < 4; ++q) {
      const int r = q * 32 + srow;
      gload_lds16(Ab + (size_t)r * K1_DIM + k0 + scol, Ad + r * 64 + scol);
      gload_lds16(Bb + (size_t)r * K1_DIM + k0 + scol, Bd + r * 64 + scol);
    }
  };

  const int wave = t >> 6;
  const int lane = t & 63;
  const int wm = (wave >> 1) * 64;
  const int wn = (wave & 1) * 64;
  const int lr = lane & 15;
  const int l4 = lane >> 4;

  f32x4 acc[4][4];
  #pragma unroll
  for (int i = 0; i < 4; ++i)
    #pragma unroll
    for (int jj = 0; jj < 4; ++jj)
      acc[i][jj] = (f32x4){0.f, 0.f, 0.f, 0.f};

  stage(0, 0);
  __syncthreads();
  int cur = 0;
  const int NT = K1_DIM / 64;            // 36
  for (int kt = 0; kt < NT; ++kt) {
    if (kt + 1 < NT) stage(cur ^ 1, kt + 1);
    const unsigned short* A0 = cur ? As1 : As0;
    const unsigned short* B0 = cur ? Bs1 : Bs0;
    #pragma unroll
    for (int ks = 0; ks < 2; ++ks) {
      bf16x8 af[4], bfv[4];
      #pragma unroll
      for (int fm = 0; fm < 4; ++fm) {
        const int r = wm + fm * 16 + lr;
        const int slot = (ks * 4 + l4) ^ (r & 7);
        af[fm] = *(const bf16x8*)(A0 + r * 64 + slot * 8);
      }
      #pragma unroll
      for (int fn = 0; fn < 4; ++fn) {
        const int r = wn + fn * 16 + lr;
        const int slot = (ks * 4 + l4) ^ (r & 7);
        bfv[fn] = *(const bf16x8*)(B0 + r * 64 + slot * 8);
      }
      #pragma unroll
      for (int fm = 0; fm < 4; ++fm)
        #pragma unroll
        for (int fn = 0; fn < 4; ++fn)
          acc[fm][fn] = MFMA(af[fm], bfv[fn], acc[fm][fn], 0, 0, 0);
    }
    __syncthreads();
    cur ^= 1;
  }

  float* Xb = X + (size_t)bm * 128 * H_DIM + bn * 128;
  #pragma unroll
  for (int fm = 0; fm < 4; ++fm) {
    const int row0 = wm + fm * 16 + l4 * 4;
    #pragma unroll
    for (int fn = 0; fn < 4; ++fn) {
      const int col = wn + fn * 16 + lr;
      #pragma unroll
      for (int r = 0; r < 4; ++r)
        Xb[(size_t)(row0 + r) * H_DIM + col] = acc[fm][fn][r];
    }
  }
}

// ---------- GEMM2 v2: h-major chunks of 96, features once, B in registers ----------
// 64 rows x 128 cols per block, 4 waves of 64x32, A-tile [64][104] in LDS only.
__global__ __launch_bounds__(256, 2) void k_gemm2(
    const float* __restrict__ X, const unsigned short* __restrict__ W2p,
    const float* __restrict__ gamma, const float* __restrict__ beta,
    float* __restrict__ out) {
  extern __shared__ unsigned short smem2[];
  unsigned short* At = smem2;            // [64][104]

  const int t = threadIdx.x;
  const int bm = blockIdx.x;             // 0..511
  const int row = t >> 2;                // local row 0..63
  const int quart = t & 3;
  const int wave = t >> 6;
  const int lane = t & 63;
  const int wn = wave * 32;
  const int lr = lane & 15;
  const int l4 = lane >> 4;

  const float* Xrow = X + (size_t)(bm * 64 + row) * H_DIM;

  // row stats (mean/var over 512), 4 threads per row — validated r11
  float s = 0.f, ss = 0.f;
  #pragma unroll 4
  for (int q = 0; q < 32; ++q) {
    float4 v = *(const float4*)(Xrow + quart * 128 + q * 4);
    s += v.x + v.y + v.z + v.w;
    ss += v.x * v.x + v.y * v.y + v.z * v.z + v.w * v.w;
  }
  s += __shfl_xor(s, 1); ss += __shfl_xor(ss, 1);
  s += __shfl_xor(s, 2); ss += __shfl_xor(ss, 2);
  const float mu = s * (1.f / 512.f);
  const float var = ss * (1.f / 512.f) - mu * mu;
  const float rstd = rsqrtf(var + 1e-5f);

  // B fragment bases (direct register loads from L2-resident W2p)
  const unsigned short* bptr0 = W2p + (size_t)(wn + lr) * K2P + l4 * 8;
  const unsigned short* bptr1 = W2p + (size_t)(wn + 16 + lr) * K2P + l4 * 8;

  bf16x8 bcur[2][3], bnxt[2][3];         // static indices only (rule #20)
  #pragma unroll
  for (int ks = 0; ks < 3; ++ks) {
    bnxt[0][ks] = *(const bf16x8*)(bptr0 + ks * 32);
    bnxt[1][ks] = *(const bf16x8*)(bptr1 + ks * 32);
  }

  const int hq = quart * 2;              // this thread's 2 h's per chunk
  float2 xp = *(const float2*)(Xrow + hq);
  float2 gp = *(const float2*)(gamma + hq);
  float2 bp = *(const float2*)(beta + hq);

  f32x4 acc[4][2];
  #pragma unroll
  for (int i = 0; i < 4; ++i)
    #pragma unroll
    for (int jj = 0; jj < 2; ++jj)
      acc[i][jj] = (f32x4){0.f, 0.f, 0.f, 0.f};

  for (int ch = 0; ch < 64; ++ch) {
    // features for 2 h's, computed ONCE (12 u16 each: [silu, p0..p7, 0,0,0])
    unsigned o[12];
    {
      float xn0 = fmaxf(fmaf((xp.x - mu) * rstd, gp.x, bp.x), 0.f);
      float xn1 = fmaxf(fmaf((xp.y - mu) * rstd, gp.y, bp.y), 0.f);
      unsigned sA, a0, a1, a2, a3, sB, b0, b1, b2, b3;
      kan_feat(xn0, sA, a0, a1, a2, a3);
      kan_feat(xn1, sB, b0, b1, b2, b3);
      o[0] = sA | (a0 << 16); o[1] = (a0 >> 16) | (a1 << 16);
      o[2] = (a1 >> 16) | (a2 << 16); o[3] = (a2 >> 16) | (a3 << 16);
      o[4] = (a3 >> 16); o[5] = 0u;
      o[6] = sB | (b0 << 16); o[7] = (b0 >> 16) | (b1 << 16);
      o[8] = (b1 >> 16) | (b2 << 16); o[9] = (b2 >> 16) | (b3 << 16);
      o[10] = (b3 >> 16); o[11] = 0u;
    }
    __syncthreads();                     // prev MFMA done; bnxt loads drained
    #pragma unroll
    for (int fn = 0; fn < 2; ++fn)
      #pragma unroll
      for (int ks = 0; ks < 3; ++ks)
        bcur[fn][ks] = bnxt[fn][ks];
    {
      uint4* da = (uint4*)(At + row * LDA2P + quart * 24);   // 48B, 16B-aligned
      da[0] = make_uint4(o[0], o[1], o[2], o[3]);
      da[1] = make_uint4(o[4], o[5], o[6], o[7]);
      da[2] = make_uint4(o[8], o[9], o[10], o[11]);
    }
    __syncthreads();                     // A-tile published
    if (ch < 63) {                       // prefetch next chunk under MFMA phase
      const int h2 = (ch + 1) * 8 + hq;
      xp = *(const float2*)(Xrow + h2);
      gp = *(const float2*)(gamma + h2);
      bp = *(const float2*)(beta + h2);
      const size_t ko = (size_t)(ch + 1) * 96;
      #pragma unroll
      for (int ks = 0; ks < 3; ++ks) {
        bnxt[0][ks] = *(const bf16x8*)(bptr0 + ko + ks * 32);
        bnxt[1][ks] = *(const bf16x8*)(bptr1 + ko + ks * 32);
      }
    }
    #pragma unroll
    for (int ks = 0; ks < 3; ++ks) {
      bf16x8 af[4];
      #pragma unroll
      for (int fm = 0; fm < 4; ++fm)
        af[fm] = *(const bf16x8*)(At + (fm * 16 + lr) * LDA2P + ks * 32 + l4 * 8);
      #pragma unroll
      for (int fm = 0; fm < 4; ++fm) {
        acc[fm][0] = MFMA(af[fm], bcur[0][ks], acc[fm][0], 0, 0, 0);
        acc[fm][1] = MFMA(af[fm], bcur[1][ks], acc[fm][1], 0, 0, 0);
      }
    }
  }

  // epilogue — byte-same indexing as validated r11
  float* mean_out = out;
  float* lstd_out = out + (size_t)N_B * A_DIM;
  #pragma unroll
  for (int fm = 0; fm < 4; ++fm) {
    const int r0 = bm * 64 + fm * 16 + l4 * 4;
    #pragma unroll
    for (int fn = 0; fn < 2; ++fn) {
      const int n = wn + fn * 16 + lr;
      #pragma unroll
      for (int r = 0; r < 4; ++r) {
        const float v = acc[fm][fn][r];
        if (n < 64) mean_out[(size_t)(r0 + r) * 64 + n] = tanhf(v);
        else lstd_out[(size_t)(r0 + r) * 64 + (n - 64)] = fminf(fmaxf(v, -20.f), 2.f);
      }
    }
  }
}

// ---------- launch ----------
extern "C" void kernel_launch(void* const* d_in, const int* in_sizes, int n_in,
                              void* d_out, int out_size, void* d_ws, size_t ws_size,
                              hipStream_t stream) {
  const float* state         = (const float*)d_in[0];
  const float* feat_base_w   = (const float*)d_in[1];
  const float* feat_spline_w = (const float*)d_in[2];
  const float* ln_gamma      = (const float*)d_in[3];
  const float* ln_beta       = (const float*)d_in[4];
  const float* mean_base_w   = (const float*)d_in[5];
  const float* mean_spline_w = (const float*)d_in[6];
  const float* lstd_base_w   = (const float*)d_in[7];
  const float* lstd_spline_w = (const float*)d_in[8];

  // workspace layout (bytes). W2p reuses the F1 region (F1 dead after gemm1,
  // prep_w2 launched after gemm1) -> NEED <= round-1's proven 221642752.
  const size_t W1_OFF  = 0;              // 512*2304*2   = 2359296
  const size_t F1_OFF  = 2359296;        // 32768*2304*2 = 150994944
  const size_t W2P_OFF = F1_OFF;         // 128*6144*2   = 1572864 (overlaps dead F1)
  const size_t X_OFF   = 153354240;      // 32768*512*4  = 67108864
  const size_t NEED    = 220463104;

  if (ws_size < NEED) {
    hipLaunchKernelGGL(k_sentinel, dim3(4096), dim3(256), 0, stream,
                       (float*)d_out, out_size);
    return;
  }

  char* ws = (char*)d_ws;
  unsigned short* W1  = (unsigned short*)(ws + W1_OFF);
  unsigned short* F1  = (unsigned short*)(ws + F1_OFF);
  unsigned short* W2p = (unsigned short*)(ws + W2P_OFF);
  float* X = (float*)(ws + X_OFF);

  hipLaunchKernelGGL(k_prep_w1, dim3(4608), dim3(256), 0, stream,
                     feat_base_w, feat_spline_w, W1);
  hipLaunchKernelGGL(k_features1, dim3(8192), dim3(256), 0, stream, state, F1);
  hipLaunchKernelGGL(k_gemm1, dim3(1024), dim3(256), 65536, stream, F1, W1, X);
  hipLaunchKernelGGL(k_prep_w2, dim3(3072), dim3(256), 0, stream,
                     mean_base_w, mean_spline_w, lstd_base_w, lstd_spline_w, W2p);
  hipLaunchKernelGGL(k_gemm2, dim3(512), dim3(256), 64 * LDA2P * 2, stream,
                     X, W2p, ln_gamma, ln_beta, (float*)d_out);
}